// Round 6
// baseline (602.661 us; speedup 1.0000x reference)
//
#include <hip/hip_runtime.h>

// CombinedLoss: 0.7*MSE + 0.3*mean_b softDTW_gamma.  B=64, T=1024, C=8, fp32.
// R6: band-split. 64 batches x 4 bands = 256 blocks (256 thr = 4 waves) -> all
// 256 CUs, 1 wave/SIMD. Wave g(=4q+w) owns rows [64g,64g+63]; skewed windows of
// 16 diagonals; intra-block halo via LDS ring + barrier; inter-block halo via
// global no-wrap ring in ws + monotonic flags (agent-scope atomics), with
// one-window flag probe + data prefetch to hide LLC latency (spin fallback).
// ws layout (floats): [0,256) mse partials | [256,320) sdtw/batch |
// [320,512) int flags | [512,512+192*2176) rings.  Needs ws >= ~1.7 MB.

constexpr int TT = 1024;
constexpr float ALPHA_ = 0.7f;
constexpr float GAMMA_ = 0.2f;
constexpr float FINF = 1000000000.0f;
constexpr int RING = 2176;          // per-boundary ring entries (abs diag k)

// lane l <- v from lane l-1; lane 0 <- old0[lane0]  (v_mov_b32 dpp wave_shr:1)
__device__ __forceinline__ float shflup1(float old0, float v) {
    return __int_as_float(__builtin_amdgcn_update_dpp(
        __float_as_int(old0), __float_as_int(v), 0x138, 0xf, 0xf, false));
}
// lane l <- v from lane l+1 (wave_shl:1); lane 63 <- 0
__device__ __forceinline__ float rotdn1(float v) {
    return __int_as_float(__builtin_amdgcn_update_dpp(
        0, __float_as_int(v), 0x130, 0xf, 0xf, false));
}

__global__ __launch_bounds__(256) void sdtw_band_kernel(
    const float* __restrict__ pred, const float* __restrict__ target,
    float* __restrict__ ws)
{
    __shared__ float4 s_p4[TT * 2];    // [-2t0..3],[-2t4..7] per column j
    __shared__ float  s_y2[TT];
    __shared__ float  s_ring[4][64];   // per-wave bottom-row ring (intra-block)
    __shared__ float  s_scr[84];       // dump area for non-lane63 halo writes
    __shared__ float  s_red[4];

    const int blk = blockIdx.x;
    const int b   = blk >> 2;          // batch
    const int q   = blk & 3;           // band
    const int tid = threadIdx.x;
    const int l   = tid & 63;
    const int w_  = __builtin_amdgcn_readfirstlane(tid >> 6);
    const int row = (q << 8) + tid;            // global row i
    const int gbase = (q << 8) + (w_ << 6);    // wave's first row

    const float* pr  = pred   + ((size_t)b * TT + row) * 8;
    const float* trm = target + ((size_t)b * TT + row) * 8;
    const float4 pa = ((const float4*)pr)[0];
    const float4 pb = ((const float4*)pr)[1];
    const float4 ma = ((const float4*)trm)[0];
    const float4 mb = ((const float4*)trm)[1];

    float x2 = 0.f, msep = 0.f;
    {
        const float pp[8] = {pa.x,pa.y,pa.z,pa.w,pb.x,pb.y,pb.z,pb.w};
        const float tt[8] = {ma.x,ma.y,ma.z,ma.w,mb.x,mb.y,mb.z,mb.w};
        #pragma unroll
        for (int c = 0; c < 8; ++c) {
            x2 = fmaf(pp[c], pp[c], x2);
            float d = pp[c] - tt[c];
            msep = fmaf(d, d, msep);
        }
    }
    // stage all 1024 target columns (each thread does 4)
    const float* tg = target + (size_t)b * TT * 8;
    #pragma unroll
    for (int c0 = 0; c0 < 4; ++c0) {
        const int col = tid + (c0 << 8);
        const float4 u0 = ((const float4*)(tg + (size_t)col * 8))[0];
        const float4 u1 = ((const float4*)(tg + (size_t)col * 8))[1];
        s_p4[2*col]   = make_float4(-2.f*u0.x, -2.f*u0.y, -2.f*u0.z, -2.f*u0.w);
        s_p4[2*col+1] = make_float4(-2.f*u1.x, -2.f*u1.y, -2.f*u1.z, -2.f*u1.w);
        float yy = u0.x*u0.x + u0.y*u0.y + u0.z*u0.z + u0.w*u0.w
                 + u1.x*u1.x + u1.y*u1.y + u1.z*u1.z + u1.w*u1.w;
        s_y2[col] = yy;
    }
    // MSE partial for this block's 256 rows
    #pragma unroll
    for (int off = 32; off > 0; off >>= 1) msep += __shfl_down(msep, off, 64);
    if (l == 0) s_red[w_] = msep;
    __syncthreads();
    if (tid == 0) ws[blk] = s_red[0] + s_red[1] + s_red[2] + s_red[3];

    int*   flags = (int*)(ws + 320);
    float* ringc = ws + 512 + (size_t)(b*3 + q - 1) * RING;  // consumer (q>0)
    float* ringp = ws + 512 + (size_t)(b*3 + q    ) * RING;  // producer (q<3)
    int* flagc = flags + b*3 + q - 1;
    int* flagp = flags + b*3 + q;
    const int flagmax = (q << 8) + TT - 2;   // producer's final khi = 256q+1022

    const float c1 = 7.213475204444817f;     // log2(e)/gamma
    const float c2 = 0.13862943611198906f;   // gamma*ln(2)
    float r1 = FINF, r2 = FINF;
    float nhv = 0.f, nhvd = 0.f;             // wave0 prefetch staging
    int havepf = 0, pf = -2000000000;
    const int lastk = gbase + 63 + TT - 1;

    for (int su = 0; su < 83; ++su) {
        const int u = su - 5 * w_;           // scalar window index
        if (u >= 0 && u <= 67) {
            const int k0 = gbase + (u << 4);
            int khi = k0 + 15; if (khi > lastk) khi = lastk;

            // ---- stage halo for this window ----
            float hv, hvd;
            if (w_ == 0) {
                if (q == 0) {
                    hv  = FINF;
                    hvd = (k0 == 0 && l == 0) ? 0.0f : FINF;
                } else {
                    const int need = min(k0 + 14, flagmax);
                    if (havepf) { hv = nhv; hvd = nhvd; havepf = 0; }
                    else {
                        if (pf < need) {
                            while (__hip_atomic_load(flagc, __ATOMIC_ACQUIRE,
                                       __HIP_MEMORY_SCOPE_AGENT) < need) {}
                        } else {
                            __builtin_amdgcn_fence(__ATOMIC_ACQUIRE, "agent");
                        }
                        hv  = __hip_atomic_load(ringc + (k0-1+l), __ATOMIC_RELAXED,
                                                __HIP_MEMORY_SCOPE_AGENT);
                        hvd = __hip_atomic_load(ringc + (k0-2+l), __ATOMIC_RELAXED,
                                                __HIP_MEMORY_SCOPE_AGENT);
                    }
                    if (u < 67) {   // probe flag for next window (overlaps loop)
                        int pl = __hip_atomic_load(flagc, __ATOMIC_RELAXED,
                                                   __HIP_MEMORY_SCOPE_AGENT);
                        pf = __builtin_amdgcn_readfirstlane(pl);
                    }
                }
            } else {
                hv  = s_ring[w_-1][(k0 - 1 + l) & 63];
                hvd = s_ring[w_-1][(k0 - 2 + l) & 63];
            }
            // halo write target: lane63 -> ring, others -> scratch (no exec games)
            float* wrp = (l == 63) ? &s_ring[w_][k0 & 63] : &s_scr[l];

            const int jbase = k0 - row;      // lane's j at d=0 (may be <0)

            #define DIAG_CORE(UP, DG, ACC, RN)                                \
                const float m_  = fminf(fminf(UP, left), DG);                 \
                const float M_  = fmaxf(fmaxf(UP, left), DG);                 \
                const float md_ = __builtin_amdgcn_fmed3f(UP, left, DG);      \
                const float mc_ = m_ * c1;                                    \
                const float e1_ = __builtin_amdgcn_exp2f(fmaf(md_, -c1, mc_));\
                const float e2_ = __builtin_amdgcn_exp2f(fmaf(M_,  -c1, mc_));\
                const float lg_ = __builtin_amdgcn_logf(1.0f + (e1_ + e2_));  \
                float RN = ACC + fmaf(-c2, lg_, m_);

            if (u >= 4 && u <= 63) {
                // ---- interior: all lanes valid, no clamp/select ----
                #pragma unroll
                for (int d = 0; d < 16; ++d) {
                    const float up   = shflup1(hv,  r1);
                    const float dg   = shflup1(hvd, r2);
                    const float left = r1;
                    hv = rotdn1(hv); hvd = rotdn1(hvd);
                    const int jj = jbase + d;
                    const float4 A  = s_p4[2*jj];
                    const float4 Bq = s_p4[2*jj+1];
                    float acc = x2 + s_y2[jj];
                    acc = fmaf(pa.x, A.x,  acc); acc = fmaf(pa.y, A.y,  acc);
                    acc = fmaf(pa.z, A.z,  acc); acc = fmaf(pa.w, A.w,  acc);
                    acc = fmaf(pb.x, Bq.x, acc); acc = fmaf(pb.y, Bq.y, acc);
                    acc = fmaf(pb.z, Bq.z, acc); acc = fmaf(pb.w, Bq.w, acc);
                    DIAG_CORE(up, dg, acc, rn)
                    r2 = r1; r1 = rn;
                    wrp[d] = rn;
                }
            } else {
                // ---- edge: clamp + validity select, dynamic length ----
                const int nd = khi - k0;     // scalar
                for (int d = 0; d <= nd; ++d) {
                    const float up   = shflup1(hv,  r1);
                    const float dg   = shflup1(hvd, r2);
                    const float left = r1;
                    hv = rotdn1(hv); hvd = rotdn1(hvd);
                    const int jj = jbase + d;
                    const int jc = min(max(jj, 0), TT - 1);
                    const float4 A  = s_p4[2*jc];
                    const float4 Bq = s_p4[2*jc+1];
                    float acc = x2 + s_y2[jc];
                    acc = fmaf(pa.x, A.x,  acc); acc = fmaf(pa.y, A.y,  acc);
                    acc = fmaf(pa.z, A.z,  acc); acc = fmaf(pa.w, A.w,  acc);
                    acc = fmaf(pb.x, Bq.x, acc); acc = fmaf(pb.y, Bq.y, acc);
                    acc = fmaf(pb.z, Bq.z, acc); acc = fmaf(pb.w, Bq.w, acc);
                    DIAG_CORE(up, dg, acc, rn0)
                    float rn = ((unsigned)jj < (unsigned)TT) ? rn0 : FINF;
                    r2 = r1; r1 = rn;
                    wrp[d] = rn;
                }
            }
            #undef DIAG_CORE

            // ---- producer: flush window to global ring + flag ----
            if (w_ == 3 && q < 3) {
                if (l < 16 && k0 + l <= khi)
                    __hip_atomic_store(ringp + (k0 + l),
                        s_ring[3][(k0 + l) & 63],
                        __ATOMIC_RELAXED, __HIP_MEMORY_SCOPE_AGENT);
                __builtin_amdgcn_fence(__ATOMIC_RELEASE, "agent");
                if (l == 0)
                    __hip_atomic_store(flagp, khi, __ATOMIC_RELAXED,
                                       __HIP_MEMORY_SCOPE_AGENT);
            }
            // ---- consumer: prefetch next window's halo if flag already there
            if (w_ == 0 && q > 0 && u < 67) {
                const int kn = k0 + 16;
                const int needn = min(kn + 14, flagmax);
                if (pf >= needn) {
                    __builtin_amdgcn_fence(__ATOMIC_ACQUIRE, "agent");
                    nhv  = __hip_atomic_load(ringc + (kn-1+l), __ATOMIC_RELAXED,
                                             __HIP_MEMORY_SCOPE_AGENT);
                    nhvd = __hip_atomic_load(ringc + (kn-2+l), __ATOMIC_RELAXED,
                                             __HIP_MEMORY_SCOPE_AGENT);
                    havepf = 1;
                }
            }
        }
        __syncthreads();
    }
    if (q == 3 && tid == 255) ws[256 + b] = r1;   // r_{2T-2}(T-1)
}

__global__ __launch_bounds__(256) void finalize2_kernel(
    const float* __restrict__ ws, float* __restrict__ out)
{
    __shared__ float sm[4], ss[4];
    const int tid = threadIdx.x, l = tid & 63, w = tid >> 6;
    float m  = ws[tid];
    float sd = (tid < 64) ? ws[256 + tid] : 0.f;
    #pragma unroll
    for (int off = 32; off > 0; off >>= 1) {
        m  += __shfl_down(m,  off, 64);
        sd += __shfl_down(sd, off, 64);
    }
    if (l == 0) { sm[w] = m; ss[w] = sd; }
    __syncthreads();
    if (tid == 0) {
        float M = sm[0] + sm[1] + sm[2] + sm[3];
        float S = ss[0] + ss[1] + ss[2] + ss[3];
        out[0] = ALPHA_ * (M / 524288.0f) + (1.0f - ALPHA_) * (S / 64.0f);
    }
}

extern "C" void kernel_launch(void* const* d_in, const int* in_sizes, int n_in,
                              void* d_out, int out_size, void* d_ws, size_t ws_size,
                              hipStream_t stream) {
    const float* pred   = (const float*)d_in[0];
    const float* target = (const float*)d_in[1];
    float* ws  = (float*)d_ws;
    float* out = (float*)d_out;

    sdtw_band_kernel<<<256, 256, 0, stream>>>(pred, target, ws);
    finalize2_kernel<<<1, 256, 0, stream>>>(ws, out);
}

// Round 7
// 443.442 us; speedup vs baseline: 1.3591x; 1.3591x over previous
//
#include <hip/hip_runtime.h>

// CombinedLoss: 0.7*MSE + 0.3*mean_b softDTW_gamma.  B=64, T=1024, C=8, fp32.
// R7: 4 bands/batch x 64 batches = 256 blocks (4 waves) -> 256 CUs, 1 wave/SIMD.
// Global wave g=4q+w owns rows [64g,64g+63]; absolute 16-diag windows; wave g
// lags g-1 by 1 window (+1 per block boundary). Intra-block halo: LDS ring.
// Cross-block halo: SELF-VALIDATING 8B atomics in ws ((tag k)<<32 | bits) --
// no fences, relaxed agent scope, per-lane tag spin + 1-window prefetch.
// t-columns flow through lanes via DPP (broadcast depth-1 prefetch from LDS):
// no per-lane LDS reads in the DP loop -> no bank conflicts.
// ws: [0,256) mse | [256,320) sdtw | u64 rings @ float-offset 320 (~1.6 MB).

constexpr int TT = 1024;
constexpr float ALPHA_ = 0.7f;
constexpr float FINF = 1000000000.0f;
constexpr int RING = 1088;
constexpr int NSTEPS = 146;

__device__ __forceinline__ float shflup1(float old0, float v) {
    return __int_as_float(__builtin_amdgcn_update_dpp(
        __float_as_int(old0), __float_as_int(v), 0x138, 0xf, 0xf, false));
}
__device__ __forceinline__ float rotdn1(float v) {
    return __int_as_float(__builtin_amdgcn_update_dpp(
        0, __float_as_int(v), 0x130, 0xf, 0xf, false));
}

__global__ __launch_bounds__(256) void sdtw_band_kernel(
    const float* __restrict__ pred, const float* __restrict__ target,
    float* __restrict__ ws)
{
    __shared__ float4 s_p4[TT * 2];    // col j: [-2t0..3],[-2t4..7]
    __shared__ float  s_y2[TT];
    __shared__ float  s_ring[4][64];   // per-wave bottom-row ring
    __shared__ float  s_scr[84];       // scratch sink for non-lane63 writes
    __shared__ float  s_red[4];

    const int blk = blockIdx.x;
    const int b   = blk & 63;                  // batch (q*64+b: same-XCD bands)
    const int q   = blk >> 6;                  // band
    const int tid = threadIdx.x;
    const int l   = tid & 63;
    const int w_  = __builtin_amdgcn_readfirstlane(tid >> 6);
    const int g   = (q << 2) + w_;             // global wave 0..15
    const int gbase = g << 6;
    const int row   = gbase + l;

    const float* pr = pred   + ((size_t)b * TT + row) * 8;
    const float* tr = target + ((size_t)b * TT + row) * 8;
    const float4 pa = ((const float4*)pr)[0];
    const float4 pb = ((const float4*)pr)[1];
    const float4 ma = ((const float4*)tr)[0];
    const float4 mb = ((const float4*)tr)[1];

    float x2 = 0.f, msep = 0.f;
    {
        const float pp[8] = {pa.x,pa.y,pa.z,pa.w,pb.x,pb.y,pb.z,pb.w};
        const float tt[8] = {ma.x,ma.y,ma.z,ma.w,mb.x,mb.y,mb.z,mb.w};
        #pragma unroll
        for (int c = 0; c < 8; ++c) {
            x2 = fmaf(pp[c], pp[c], x2);
            float d = pp[c] - tt[c];
            msep = fmaf(d, d, msep);
        }
    }
    // stage all 1024 columns (4 per thread)
    const float* tg = target + (size_t)b * TT * 8;
    #pragma unroll
    for (int c0 = 0; c0 < 4; ++c0) {
        const int col = tid + (c0 << 8);
        const float4 u0 = ((const float4*)(tg + (size_t)col * 8))[0];
        const float4 u1 = ((const float4*)(tg + (size_t)col * 8))[1];
        s_p4[2*col]   = make_float4(-2.f*u0.x, -2.f*u0.y, -2.f*u0.z, -2.f*u0.w);
        s_p4[2*col+1] = make_float4(-2.f*u1.x, -2.f*u1.y, -2.f*u1.z, -2.f*u1.w);
        s_y2[col] = u0.x*u0.x + u0.y*u0.y + u0.z*u0.z + u0.w*u0.w
                  + u1.x*u1.x + u1.y*u1.y + u1.z*u1.z + u1.w*u1.w;
    }
    #pragma unroll
    for (int off = 32; off > 0; off >>= 1) msep += __shfl_down(msep, off, 64);
    if (l == 0) s_red[w_] = msep;
    __syncthreads();
    if (tid == 0) ws[blk] = s_red[0] + s_red[1] + s_red[2] + s_red[3];

    unsigned long long* rings = (unsigned long long*)(ws + 320);
    unsigned long long* pub = rings + (size_t)(q * 64 + b) * RING;       // w_==3,q<3
    unsigned long long* con = rings + (size_t)((q - 1) * 64 + b) * RING; // w_==0,q>0
    const int kb_pub   = 256 * q + 192;
    const int kb_con   = 256 * q - 64;
    const int kmax_con = kb_con + 1086;

    const float c1 = 7.213475204444817f;     // log2(e)/gamma
    const float c2 = 0.13862943611198906f;   // gamma*ln(2)
    const int amin = g << 2;                 // first abs window = 4g
    const int amax = amin + 67;

    float r1 = FINF, r2 = FINF;
    float tf0=0,tf1=0,tf2=0,tf3=0,tf4=0,tf5=0,tf6=0,tf7=0, y2f=0;
    int jj0 = 0;                             // column held in A0/B0/ya
    float4 A0 = s_p4[0], B0 = s_p4[1], A1 = s_p4[2], B1 = s_p4[3];
    float  ya = s_y2[0], yb = s_y2[1];
    unsigned long long pe1 = 0, pe2 = 0;
    int ppf = 0;

    for (int s = 0; s < NSTEPS; ++s) {
        const int a = s - g - q;                     // scalar window id
        if (a >= amin && a <= amax) {
            const int k0 = a << 4;
            const int u  = a - amin;                 // 0..67
            const int ndv = (u == 67) ? 14 : 15;     // last diag offset

            // ---- stage halo hv (diag k-1) / hvd (diag k-2), row gbase-1 ----
            float hv, hvd;
            if (w_ == 0) {
                if (q == 0) {
                    hv  = FINF;
                    hvd = (u == 0 && l == 0) ? 0.0f : FINF;
                } else {
                    const int kk1 = k0 - 1 + l, kk2 = k0 - 2 + l;
                    const int id1 = min(kk1 - kb_con, RING - 1);
                    const int id2 = min(kk2 - kb_con, RING - 1);
                    const bool n1 = (l < 16) && (kk1 <= kmax_con);
                    const bool n2 = (l < 16) && (kk2 <= kmax_con);
                    unsigned long long e1, e2;
                    if (ppf) { e1 = pe1; e2 = pe2; ppf = 0; }
                    else {
                        e1 = __hip_atomic_load(con + id1, __ATOMIC_RELAXED,
                                               __HIP_MEMORY_SCOPE_AGENT);
                        e2 = __hip_atomic_load(con + id2, __ATOMIC_RELAXED,
                                               __HIP_MEMORY_SCOPE_AGENT);
                    }
                    while (!__all(((!n1) | ((int)(e1 >> 32) == kk1)) &
                                  ((!n2) | ((int)(e2 >> 32) == kk2)))) {
                        e1 = __hip_atomic_load(con + id1, __ATOMIC_RELAXED,
                                               __HIP_MEMORY_SCOPE_AGENT);
                        e2 = __hip_atomic_load(con + id2, __ATOMIC_RELAXED,
                                               __HIP_MEMORY_SCOPE_AGENT);
                    }
                    hv  = n1 ? __uint_as_float((unsigned)e1) : FINF;
                    hvd = n2 ? __uint_as_float((unsigned)e2) : FINF;
                }
            } else {
                hv  = s_ring[w_ - 1][(k0 - 1 + l) & 63];
                hvd = s_ring[w_ - 1][(k0 - 2 + l) & 63];
            }
            float* wrp = (l == 63) ? &s_ring[w_][k0 & 63] : &s_scr[l];

            auto diag = [&](int d, bool edge_) {
                tf0 = shflup1(A0.x, tf0); tf1 = shflup1(A0.y, tf1);
                tf2 = shflup1(A0.z, tf2); tf3 = shflup1(A0.w, tf3);
                tf4 = shflup1(B0.x, tf4); tf5 = shflup1(B0.y, tf5);
                tf6 = shflup1(B0.z, tf6); tf7 = shflup1(B0.w, tf7);
                y2f = shflup1(ya, y2f);
                const float up   = shflup1(hv,  r1);
                const float dg   = shflup1(hvd, r2);
                const float left = r1;
                hv = rotdn1(hv); hvd = rotdn1(hvd);
                A0 = A1; B0 = B1; ya = yb;
                jj0 = min(jj0 + 1, TT - 1);
                const int jn = min(jj0 + 1, TT - 1);
                A1 = s_p4[2*jn]; B1 = s_p4[2*jn + 1]; yb = s_y2[jn];
                float acc = x2 + y2f;
                acc = fmaf(pa.x, tf0, acc); acc = fmaf(pa.y, tf1, acc);
                acc = fmaf(pa.z, tf2, acc); acc = fmaf(pa.w, tf3, acc);
                acc = fmaf(pb.x, tf4, acc); acc = fmaf(pb.y, tf5, acc);
                acc = fmaf(pb.z, tf6, acc); acc = fmaf(pb.w, tf7, acc);
                const float m  = fminf(fminf(up, left), dg);
                const float M  = fmaxf(fmaxf(up, left), dg);
                const float md = __builtin_amdgcn_fmed3f(up, left, dg);
                const float mc = m * c1;
                const float e1 = __builtin_amdgcn_exp2f(fmaf(md, -c1, mc));
                const float e2 = __builtin_amdgcn_exp2f(fmaf(M,  -c1, mc));
                const float lg = __builtin_amdgcn_logf(1.0f + (e1 + e2));
                float rn = acc + fmaf(-c2, lg, m);
                if (edge_) {
                    const int jj = k0 + d - row;
                    rn = ((unsigned)jj < (unsigned)TT) ? rn : FINF;
                }
                r2 = r1; r1 = rn;
                wrp[d] = rn;
            };

            if (u >= 4 && u <= 63) {
                #pragma unroll
                for (int d = 0; d < 16; ++d) diag(d, false);
            } else {
                for (int d = 0; d <= ndv; ++d) diag(d, true);
            }

            // ---- producer: publish window as self-validating u64 entries ----
            if (w_ == 3 && q < 3) {
                if (l <= ndv) {
                    const int kk = k0 + l;
                    const unsigned long long ev =
                        ((unsigned long long)(unsigned)kk << 32) |
                        (unsigned long long)__float_as_uint(s_ring[3][kk & 63]);
                    __hip_atomic_store(pub + (kk - kb_pub), ev,
                                       __ATOMIC_RELAXED, __HIP_MEMORY_SCOPE_AGENT);
                }
            }
            // ---- consumer: prefetch next window's halo entries ----
            if (w_ == 0 && q > 0 && a < amax) {
                const int k0n = k0 + 16;
                const int kk1 = k0n - 1 + l, kk2 = k0n - 2 + l;
                pe1 = __hip_atomic_load(con + min(kk1 - kb_con, RING - 1),
                                        __ATOMIC_RELAXED, __HIP_MEMORY_SCOPE_AGENT);
                pe2 = __hip_atomic_load(con + min(kk2 - kb_con, RING - 1),
                                        __ATOMIC_RELAXED, __HIP_MEMORY_SCOPE_AGENT);
                ppf = 1;
            }
        }
        __syncthreads();
    }
    if (q == 3 && tid == 255) ws[256 + b] = r1;      // r_{2T-2}(T-1)
}

__global__ __launch_bounds__(256) void finalize2_kernel(
    const float* __restrict__ ws, float* __restrict__ out)
{
    __shared__ float sm[4], ss[4];
    const int tid = threadIdx.x, l = tid & 63, w = tid >> 6;
    float m  = ws[tid];
    float sd = (tid < 64) ? ws[256 + tid] : 0.f;
    #pragma unroll
    for (int off = 32; off > 0; off >>= 1) {
        m  += __shfl_down(m,  off, 64);
        sd += __shfl_down(sd, off, 64);
    }
    if (l == 0) { sm[w] = m; ss[w] = sd; }
    __syncthreads();
    if (tid == 0) {
        float M = sm[0] + sm[1] + sm[2] + sm[3];
        float S = ss[0] + ss[1] + ss[2] + ss[3];
        out[0] = ALPHA_ * (M / 524288.0f) + (1.0f - ALPHA_) * (S / 64.0f);
    }
}

extern "C" void kernel_launch(void* const* d_in, const int* in_sizes, int n_in,
                              void* d_out, int out_size, void* d_ws, size_t ws_size,
                              hipStream_t stream) {
    const float* pred   = (const float*)d_in[0];
    const float* target = (const float*)d_in[1];
    float* ws  = (float*)d_ws;
    float* out = (float*)d_out;

    sdtw_band_kernel<<<256, 256, 0, stream>>>(pred, target, ws);
    finalize2_kernel<<<1, 256, 0, stream>>>(ws, out);
}